// Round 3
// baseline (329.932 us; speedup 1.0000x reference)
//
#include <hip/hip_runtime.h>
#include <hip/hip_cooperative_groups.h>
#include <math.h>

namespace cg = cooperative_groups;

#define N_NODES 10000
#define WPR 313            // ceil(10000/32) bitmap words per row
#define CAP 96             // neighbor capacity (deg ~ mean 32, sd 5.7; 96 = +11 sd)
#define NBLK 256
#define NTHR 256
#define NTOT (NBLK * NTHR)
#define NWAVES (NBLK * (NTHR / 64))   // 1024
#define BN_EPS 1e-5f
#define DEG_EPS 1e-8f

struct Params {
    const float* x; const int* e; int E;
    const float* W0; const float* b0; const float* g0; const float* be0;
    const float* W1; const float* b1; const float* g1; const float* be1;
    const float* Wo; const float* bo; const float* Wa; const float* ba;
    float* out;
    unsigned* bm; int* nbr; int* cnt; float* dinv; float* xs;
    float* hA; float* hB; float* hBs;
    float* p1s; float* p1q; float* p2s; float* p2q;   // [32 * NBLK] each
};

__global__ void __launch_bounds__(NTHR) fused_gnn(Params p) {
    cg::grid_group grid = cg::this_grid();
    const int tid  = threadIdx.x;
    const int blk  = blockIdx.x;
    const int g    = blk * NTHR + tid;
    const int lane = tid & 63;
    const int gw   = blk * (NTHR / 64) + (tid >> 6);  // global wave id

    __shared__ float lds0[256], lds1[256];
    __shared__ float sc[32], sh[32];

    // ---------- phase 0: clear bitmap ----------
    {
        uint4* bm4 = (uint4*)p.bm;
        const int n16 = N_NODES * WPR / 4;   // 782500 exactly
        for (int t = g; t < n16; t += NTOT) bm4[t] = make_uint4(0u, 0u, 0u, 0u);
    }
    grid.sync();

    // ---------- phase 1: scatter edges (SET semantics, idempotent atomicOr) ----------
    for (int t = g; t < p.E; t += NTOT) {
        int s = p.e[t];
        int d = p.e[p.E + t];
        atomicOr(&p.bm[(size_t)s * WPR + (d >> 5)], 1u << (d & 31));
    }
    grid.sync();

    // ---------- phase 2: bitmap -> CSR + dinv + prescaled x ----------
    for (int i = gw; i < N_NODES; i += NWAVES) {
        const unsigned* row = p.bm + (size_t)i * WPR;
        int* outl = p.nbr + (size_t)i * CAP;
        int running = 0;
        #pragma unroll
        for (int step = 0; step < 5; ++step) {       // 5*64 = 320 >= 313
            int w = step * 64 + lane;
            unsigned bits = (w < WPR) ? row[w] : 0u;
            int n = __popc(bits);
            int off = n;
            #pragma unroll
            for (int d = 1; d < 64; d <<= 1) {
                int v = __shfl_up(off, d);
                if (lane >= d) off += v;
            }
            int total = __shfl(off, 63);
            int slot = running + off - n;             // exclusive prefix
            while (bits) {
                int b = __ffs(bits) - 1; bits &= bits - 1;
                if (slot < CAP) outl[slot] = (w << 5) + b;
                slot++;
            }
            running += total;
        }
        float di = rsqrtf((float)(running + 1) + DEG_EPS);  // +1 from identity
        if (lane == 0) { p.cnt[i] = running < CAP ? running : CAP; p.dinv[i] = di; }
        if (lane < 6) p.xs[(size_t)i * 6 + lane] = di * p.x[(size_t)i * 6 + lane];
    }
    grid.sync();

    // ---------- phase 3: agg1 + GEMM W0 (6x32) + BN1 block partials ----------
    {
        float ps = 0.f, pq = 0.f;     // feature = lane (valid lane<32)
        for (int i = gw; i < N_NODES; i += NWAVES) {
            int c = p.cnt[i];
            const int* lst = p.nbr + (size_t)i * CAP;
            float acc[6] = {0.f, 0.f, 0.f, 0.f, 0.f, 0.f};
            for (int k = lane; k < c; k += 64) {
                int j = lst[k];
                const float* xj = p.xs + (size_t)j * 6;
                #pragma unroll
                for (int d = 0; d < 6; ++d) acc[d] += xj[d];
            }
            #pragma unroll
            for (int d = 0; d < 6; ++d) {
                #pragma unroll
                for (int off = 32; off; off >>= 1) acc[d] += __shfl_xor(acc[d], off);
            }
            float di = p.dinv[i];
            if (lane < 32) {
                float s = p.b0[lane];
                #pragma unroll
                for (int d = 0; d < 6; ++d)
                    s += (acc[d] + p.xs[(size_t)i * 6 + d]) * di * p.W0[d * 32 + lane];
                p.hA[(size_t)i * 32 + lane] = s;
                ps += s; pq += s * s;
            }
        }
        lds0[tid] = ps; lds1[tid] = pq;
        __syncthreads();
        if (tid < 32) {
            float s = 0.f, q = 0.f;
            #pragma unroll
            for (int w = 0; w < 4; ++w) {
                s += lds0[w * 64 + tid] + lds0[w * 64 + 32 + tid];
                q += lds1[w * 64 + tid] + lds1[w * 64 + 32 + tid];
            }
            p.p1s[tid * NBLK + blk] = s;
            p.p1q[tid * NBLK + blk] = q;
        }
    }
    grid.sync();

    // ---------- phase 4: reduce BN1 (redundant per block, fixed order) + apply ----------
    {
        int f = tid & 31, gg = tid >> 5;              // gg: 0..7
        float s = 0.f, q = 0.f;
        for (int b = gg * 32; b < gg * 32 + 32; ++b) {
            s += p.p1s[f * NBLK + b];
            q += p.p1q[f * NBLK + b];
        }
        lds0[tid] = s; lds1[tid] = q;
        __syncthreads();
        if (tid < 32) {
            float S = 0.f, Q = 0.f;
            #pragma unroll
            for (int k = 0; k < 8; ++k) { S += lds0[k * 32 + tid]; Q += lds1[k * 32 + tid]; }
            float mu = S / (float)N_NODES;
            float var = Q / (float)N_NODES - mu * mu;   // biased
            float rstd = rsqrtf(var + BN_EPS);
            float scale = p.g0[tid] * rstd;
            sc[tid] = scale; sh[tid] = p.be0[tid] - mu * scale;
        }
        __syncthreads();
        for (int idx = g; idx < N_NODES * 32; idx += NTOT) {
            int f2 = idx & 31;
            float v = p.hA[idx] * sc[f2] + sh[f2];
            v = v > 0.f ? v : 0.f;
            p.hB[idx] = v;                            // layer-1 output (residual input)
            p.hBs[idx] = v * p.dinv[idx >> 5];        // dinv-prescaled for agg2
        }
    }
    grid.sync();

    // ---------- phase 5: agg2 + GEMM W1 (32x32) + BN2 block partials ----------
    {
        float ps = 0.f, pq = 0.f;
        const int f = lane & 31;
        const int half = lane >> 5;
        for (int i = gw; i < N_NODES; i += NWAVES) {
            int c = p.cnt[i];
            const int* lst = p.nbr + (size_t)i * CAP;
            float acc = 0.f;
            for (int k = half; k < c; k += 2)
                acc += p.hBs[(size_t)lst[k] * 32 + f];
            acc += __shfl_xor(acc, 32);
            float t = (acc + p.hBs[(size_t)i * 32 + f]) * p.dinv[i];
            float part = 0.f;
            int fbase = half * 16;
            #pragma unroll
            for (int k = 0; k < 16; ++k) {
                float tf = __shfl(t, fbase + k);
                part += tf * p.W1[(fbase + k) * 32 + f];
            }
            part += __shfl_xor(part, 32);
            if (lane < 32) {
                float s = p.b1[f] + part;
                p.hA[(size_t)i * 32 + f] = s;
                ps += s; pq += s * s;
            }
        }
        lds0[tid] = ps; lds1[tid] = pq;
        __syncthreads();
        if (tid < 32) {
            float s = 0.f, q = 0.f;
            #pragma unroll
            for (int w = 0; w < 4; ++w) {
                s += lds0[w * 64 + tid] + lds0[w * 64 + 32 + tid];
                q += lds1[w * 64 + tid] + lds1[w * 64 + 32 + tid];
            }
            p.p2s[tid * NBLK + blk] = s;
            p.p2q[tid * NBLK + blk] = q;
        }
    }
    grid.sync();

    // ---------- phase 6: reduce BN2 (redundant) + BN2/ReLU/residual + heads ----------
    {
        int f = tid & 31, gg = tid >> 5;
        float s = 0.f, q = 0.f;
        for (int b = gg * 32; b < gg * 32 + 32; ++b) {
            s += p.p2s[f * NBLK + b];
            q += p.p2q[f * NBLK + b];
        }
        lds0[tid] = s; lds1[tid] = q;
        __syncthreads();
        if (tid < 32) {
            float S = 0.f, Q = 0.f;
            #pragma unroll
            for (int k = 0; k < 8; ++k) { S += lds0[k * 32 + tid]; Q += lds1[k * 32 + tid]; }
            float mu = S / (float)N_NODES;
            float var = Q / (float)N_NODES - mu * mu;
            float rstd = rsqrtf(var + BN_EPS);
            float scale = p.g1[tid] * rstd;
            sc[tid] = scale; sh[tid] = p.be1[tid] - mu * scale;
        }
        __syncthreads();
        const int r0 = g >> 5;          // 32-lane group per row
        const int l = g & 31;
        for (int r = r0; r < N_NODES; r += NTOT / 32) {
            int idx = r * 32 + l;
            float v = p.hA[idx] * sc[l] + sh[l];
            v = v > 0.f ? v : 0.f;
            v += p.hB[idx];                           // residual -> final h
            float q0 = v * p.Wo[l * 2 + 0];
            float q1 = v * p.Wo[l * 2 + 1];
            float qa = v * p.Wa[l];
            #pragma unroll
            for (int off = 16; off; off >>= 1) {
                q0 += __shfl_xor(q0, off);
                q1 += __shfl_xor(q1, off);
                qa += __shfl_xor(qa, off);
            }
            if (l == 0) {
                p.out[(size_t)r * 2 + 0] = q0 + p.bo[0];
                p.out[(size_t)r * 2 + 1] = q1 + p.bo[1];
                p.out[2 * N_NODES + r] = 1.f / (1.f + expf(-(qa + p.ba[0])));
            }
        }
    }
}

extern "C" void kernel_launch(void* const* d_in, const int* in_sizes, int n_in,
                              void* d_out, int out_size, void* d_ws, size_t ws_size,
                              hipStream_t stream) {
    Params prm;
    prm.x   = (const float*)d_in[0];
    prm.e   = (const int*)d_in[1];
    prm.E   = in_sizes[1] / 2;
    prm.W0  = (const float*)d_in[2];
    prm.b0  = (const float*)d_in[3];
    prm.g0  = (const float*)d_in[4];
    prm.be0 = (const float*)d_in[5];
    prm.W1  = (const float*)d_in[6];
    prm.b1  = (const float*)d_in[7];
    prm.g1  = (const float*)d_in[8];
    prm.be1 = (const float*)d_in[9];
    prm.Wo  = (const float*)d_in[10];
    prm.bo  = (const float*)d_in[11];
    prm.Wa  = (const float*)d_in[12];
    prm.ba  = (const float*)d_in[13];
    prm.out = (float*)d_out;

    char* ws = (char*)d_ws;
    size_t off = 0;
    auto take = [&](size_t bytes) { char* q = ws + off; off += (bytes + 255) & ~(size_t)255; return q; };
    prm.bm   = (unsigned*)take((size_t)N_NODES * WPR * 4);   // 12.52 MB
    prm.nbr  = (int*)take((size_t)N_NODES * CAP * 4);        // 3.84 MB
    prm.cnt  = (int*)take((size_t)N_NODES * 4);
    prm.dinv = (float*)take((size_t)N_NODES * 4);
    prm.xs   = (float*)take((size_t)N_NODES * 6 * 4);
    prm.hA   = (float*)take((size_t)N_NODES * 32 * 4);
    prm.hB   = (float*)take((size_t)N_NODES * 32 * 4);
    prm.hBs  = (float*)take((size_t)N_NODES * 32 * 4);
    prm.p1s  = (float*)take(32 * NBLK * 4);
    prm.p1q  = (float*)take(32 * NBLK * 4);
    prm.p2s  = (float*)take(32 * NBLK * 4);
    prm.p2q  = (float*)take(32 * NBLK * 4);

    void* args[] = { &prm };
    hipLaunchCooperativeKernel((const void*)fused_gnn, dim3(NBLK), dim3(NTHR),
                               args, 0, stream);
}

// Round 4
// 329.916 us; speedup vs baseline: 1.0000x; 1.0000x over previous
//
#include <hip/hip_runtime.h>
#include <hip/hip_cooperative_groups.h>
#include <math.h>

namespace cg = cooperative_groups;

#define N_NODES 10000
#define WPR 313            // ceil(10000/32) bitmap words per row
#define CAP 96             // neighbor capacity (deg ~ mean 32, sd 5.7; 96 = +11 sd)
#define NBLK 256
#define NTHR 256
#define NTOT (NBLK * NTHR)
#define NWAVES (NBLK * (NTHR / 64))   // 1024
#define BN_EPS 1e-5f
#define DEG_EPS 1e-8f

struct Params {
    const float* x; const int* e; int E;
    const float* W0; const float* b0; const float* g0; const float* be0;
    const float* W1; const float* b1; const float* g1; const float* be1;
    const float* Wo; const float* bo; const float* Wa; const float* ba;
    float* out;
    unsigned* bm; int* nbr; int* cnt; float* dinv; float* xs;
    float* hA; float* hB; float* hBs;
    float* p1s; float* p1q; float* p2s; float* p2q;   // [32 * NBLK] each
};

__global__ void __launch_bounds__(NTHR) fused_gnn(Params p) {
    cg::grid_group grid = cg::this_grid();
    const int tid  = threadIdx.x;
    const int blk  = blockIdx.x;
    const int g    = blk * NTHR + tid;
    const int lane = tid & 63;
    const int gw   = blk * (NTHR / 64) + (tid >> 6);  // global wave id

    __shared__ float lds0[256], lds1[256];
    __shared__ float sc[32], sh[32];

    // ---------- phase 0: clear bitmap ----------
    {
        uint4* bm4 = (uint4*)p.bm;
        const int n16 = N_NODES * WPR / 4;   // 782500 exactly
        for (int t = g; t < n16; t += NTOT) bm4[t] = make_uint4(0u, 0u, 0u, 0u);
    }
    grid.sync();

    // ---------- phase 1: scatter edges (SET semantics, idempotent atomicOr) ----------
    for (int t = g; t < p.E; t += NTOT) {
        int s = p.e[t];
        int d = p.e[p.E + t];
        atomicOr(&p.bm[(size_t)s * WPR + (d >> 5)], 1u << (d & 31));
    }
    grid.sync();

    // ---------- phase 2: bitmap -> CSR + dinv + prescaled x ----------
    for (int i = gw; i < N_NODES; i += NWAVES) {
        const unsigned* row = p.bm + (size_t)i * WPR;
        int* outl = p.nbr + (size_t)i * CAP;
        int running = 0;
        #pragma unroll
        for (int step = 0; step < 5; ++step) {       // 5*64 = 320 >= 313
            int w = step * 64 + lane;
            unsigned bits = (w < WPR) ? row[w] : 0u;
            int n = __popc(bits);
            int off = n;
            #pragma unroll
            for (int d = 1; d < 64; d <<= 1) {
                int v = __shfl_up(off, d);
                if (lane >= d) off += v;
            }
            int total = __shfl(off, 63);
            int slot = running + off - n;             // exclusive prefix
            while (bits) {
                int b = __ffs(bits) - 1; bits &= bits - 1;
                if (slot < CAP) outl[slot] = (w << 5) + b;
                slot++;
            }
            running += total;
        }
        float di = rsqrtf((float)(running + 1) + DEG_EPS);  // +1 from identity
        if (lane == 0) { p.cnt[i] = running < CAP ? running : CAP; p.dinv[i] = di; }
        if (lane < 6) p.xs[(size_t)i * 6 + lane] = di * p.x[(size_t)i * 6 + lane];
    }
    grid.sync();

    // ---------- phase 3: agg1 + GEMM W0 (6x32) + BN1 block partials ----------
    {
        float ps = 0.f, pq = 0.f;     // feature = lane (valid lane<32)
        for (int i = gw; i < N_NODES; i += NWAVES) {
            int c = p.cnt[i];
            const int* lst = p.nbr + (size_t)i * CAP;
            float acc[6] = {0.f, 0.f, 0.f, 0.f, 0.f, 0.f};
            for (int k = lane; k < c; k += 64) {
                int j = lst[k];
                const float* xj = p.xs + (size_t)j * 6;
                #pragma unroll
                for (int d = 0; d < 6; ++d) acc[d] += xj[d];
            }
            #pragma unroll
            for (int d = 0; d < 6; ++d) {
                #pragma unroll
                for (int off = 32; off; off >>= 1) acc[d] += __shfl_xor(acc[d], off);
            }
            float di = p.dinv[i];
            if (lane < 32) {
                float s = p.b0[lane];
                #pragma unroll
                for (int d = 0; d < 6; ++d)
                    s += (acc[d] + p.xs[(size_t)i * 6 + d]) * di * p.W0[d * 32 + lane];
                p.hA[(size_t)i * 32 + lane] = s;
                ps += s; pq += s * s;
            }
        }
        lds0[tid] = ps; lds1[tid] = pq;
        __syncthreads();
        if (tid < 32) {
            float s = 0.f, q = 0.f;
            #pragma unroll
            for (int w = 0; w < 4; ++w) {
                s += lds0[w * 64 + tid] + lds0[w * 64 + 32 + tid];
                q += lds1[w * 64 + tid] + lds1[w * 64 + 32 + tid];
            }
            p.p1s[tid * NBLK + blk] = s;
            p.p1q[tid * NBLK + blk] = q;
        }
    }
    grid.sync();

    // ---------- phase 4: reduce BN1 (redundant per block, fixed order) + apply ----------
    {
        int f = tid & 31, gg = tid >> 5;              // gg: 0..7
        float s = 0.f, q = 0.f;
        for (int b = gg * 32; b < gg * 32 + 32; ++b) {
            s += p.p1s[f * NBLK + b];
            q += p.p1q[f * NBLK + b];
        }
        lds0[tid] = s; lds1[tid] = q;
        __syncthreads();
        if (tid < 32) {
            float S = 0.f, Q = 0.f;
            #pragma unroll
            for (int k = 0; k < 8; ++k) { S += lds0[k * 32 + tid]; Q += lds1[k * 32 + tid]; }
            float mu = S / (float)N_NODES;
            float var = Q / (float)N_NODES - mu * mu;   // biased
            float rstd = rsqrtf(var + BN_EPS);
            float scale = p.g0[tid] * rstd;
            sc[tid] = scale; sh[tid] = p.be0[tid] - mu * scale;
        }
        __syncthreads();
        for (int idx = g; idx < N_NODES * 32; idx += NTOT) {
            int f2 = idx & 31;
            float v = p.hA[idx] * sc[f2] + sh[f2];
            v = v > 0.f ? v : 0.f;
            p.hB[idx] = v;                            // layer-1 output (residual input)
            p.hBs[idx] = v * p.dinv[idx >> 5];        // dinv-prescaled for agg2
        }
    }
    grid.sync();

    // ---------- phase 5: agg2 + GEMM W1 (32x32) + BN2 block partials ----------
    {
        float ps = 0.f, pq = 0.f;
        const int f = lane & 31;
        const int half = lane >> 5;
        for (int i = gw; i < N_NODES; i += NWAVES) {
            int c = p.cnt[i];
            const int* lst = p.nbr + (size_t)i * CAP;
            float acc = 0.f;
            for (int k = half; k < c; k += 2)
                acc += p.hBs[(size_t)lst[k] * 32 + f];
            acc += __shfl_xor(acc, 32);
            float t = (acc + p.hBs[(size_t)i * 32 + f]) * p.dinv[i];
            float part = 0.f;
            int fbase = half * 16;
            #pragma unroll
            for (int k = 0; k < 16; ++k) {
                float tf = __shfl(t, fbase + k);
                part += tf * p.W1[(fbase + k) * 32 + f];
            }
            part += __shfl_xor(part, 32);
            if (lane < 32) {
                float s = p.b1[f] + part;
                p.hA[(size_t)i * 32 + f] = s;
                ps += s; pq += s * s;
            }
        }
        lds0[tid] = ps; lds1[tid] = pq;
        __syncthreads();
        if (tid < 32) {
            float s = 0.f, q = 0.f;
            #pragma unroll
            for (int w = 0; w < 4; ++w) {
                s += lds0[w * 64 + tid] + lds0[w * 64 + 32 + tid];
                q += lds1[w * 64 + tid] + lds1[w * 64 + 32 + tid];
            }
            p.p2s[tid * NBLK + blk] = s;
            p.p2q[tid * NBLK + blk] = q;
        }
    }
    grid.sync();

    // ---------- phase 6: reduce BN2 (redundant) + BN2/ReLU/residual + heads ----------
    {
        int f = tid & 31, gg = tid >> 5;
        float s = 0.f, q = 0.f;
        for (int b = gg * 32; b < gg * 32 + 32; ++b) {
            s += p.p2s[f * NBLK + b];
            q += p.p2q[f * NBLK + b];
        }
        lds0[tid] = s; lds1[tid] = q;
        __syncthreads();
        if (tid < 32) {
            float S = 0.f, Q = 0.f;
            #pragma unroll
            for (int k = 0; k < 8; ++k) { S += lds0[k * 32 + tid]; Q += lds1[k * 32 + tid]; }
            float mu = S / (float)N_NODES;
            float var = Q / (float)N_NODES - mu * mu;
            float rstd = rsqrtf(var + BN_EPS);
            float scale = p.g1[tid] * rstd;
            sc[tid] = scale; sh[tid] = p.be1[tid] - mu * scale;
        }
        __syncthreads();
        const int r0 = g >> 5;          // 32-lane group per row
        const int l = g & 31;
        for (int r = r0; r < N_NODES; r += NTOT / 32) {
            int idx = r * 32 + l;
            float v = p.hA[idx] * sc[l] + sh[l];
            v = v > 0.f ? v : 0.f;
            v += p.hB[idx];                           // residual -> final h
            float q0 = v * p.Wo[l * 2 + 0];
            float q1 = v * p.Wo[l * 2 + 1];
            float qa = v * p.Wa[l];
            #pragma unroll
            for (int off = 16; off; off >>= 1) {
                q0 += __shfl_xor(q0, off);
                q1 += __shfl_xor(q1, off);
                qa += __shfl_xor(qa, off);
            }
            if (l == 0) {
                p.out[(size_t)r * 2 + 0] = q0 + p.bo[0];
                p.out[(size_t)r * 2 + 1] = q1 + p.bo[1];
                p.out[2 * N_NODES + r] = 1.f / (1.f + expf(-(qa + p.ba[0])));
            }
        }
    }
}

extern "C" void kernel_launch(void* const* d_in, const int* in_sizes, int n_in,
                              void* d_out, int out_size, void* d_ws, size_t ws_size,
                              hipStream_t stream) {
    Params prm;
    prm.x   = (const float*)d_in[0];
    prm.e   = (const int*)d_in[1];
    prm.E   = in_sizes[1] / 2;
    prm.W0  = (const float*)d_in[2];
    prm.b0  = (const float*)d_in[3];
    prm.g0  = (const float*)d_in[4];
    prm.be0 = (const float*)d_in[5];
    prm.W1  = (const float*)d_in[6];
    prm.b1  = (const float*)d_in[7];
    prm.g1  = (const float*)d_in[8];
    prm.be1 = (const float*)d_in[9];
    prm.Wo  = (const float*)d_in[10];
    prm.bo  = (const float*)d_in[11];
    prm.Wa  = (const float*)d_in[12];
    prm.ba  = (const float*)d_in[13];
    prm.out = (float*)d_out;

    char* ws = (char*)d_ws;
    size_t off = 0;
    auto take = [&](size_t bytes) { char* q = ws + off; off += (bytes + 255) & ~(size_t)255; return q; };
    prm.bm   = (unsigned*)take((size_t)N_NODES * WPR * 4);   // 12.52 MB
    prm.nbr  = (int*)take((size_t)N_NODES * CAP * 4);        // 3.84 MB
    prm.cnt  = (int*)take((size_t)N_NODES * 4);
    prm.dinv = (float*)take((size_t)N_NODES * 4);
    prm.xs   = (float*)take((size_t)N_NODES * 6 * 4);
    prm.hA   = (float*)take((size_t)N_NODES * 32 * 4);
    prm.hB   = (float*)take((size_t)N_NODES * 32 * 4);
    prm.hBs  = (float*)take((size_t)N_NODES * 32 * 4);
    prm.p1s  = (float*)take(32 * NBLK * 4);
    prm.p1q  = (float*)take(32 * NBLK * 4);
    prm.p2s  = (float*)take(32 * NBLK * 4);
    prm.p2q  = (float*)take(32 * NBLK * 4);

    void* args[] = { &prm };
    hipLaunchCooperativeKernel((const void*)fused_gnn, dim3(NBLK), dim3(NTHR),
                               args, 0, stream);
}

// Round 6
// 109.990 us; speedup vs baseline: 2.9997x; 2.9995x over previous
//
#include <hip/hip_runtime.h>
#include <math.h>

#define N_NODES 10000
#define WPR 320            // padded: 1280B-aligned bitmap rows, 5*64 covers exactly
#define CAP 96             // neighbor capacity (deg ~ mean 32, sd 5.7; max ~56 expected)
#define BN_EPS 1e-5f
#define DEG_EPS 1e-8f
#define NAGG 512           // blocks for agg kernels (2048 waves, 8 waves/CU)
#define NAPL 320           // blocks for apply/final kernels

// ---------------- scatter edges (SET semantics via atomicOr) ----------------
__global__ void __launch_bounds__(256) scatter_edges(const int* __restrict__ e, int E,
                                                     unsigned* __restrict__ bm) {
    int t = blockIdx.x * blockDim.x + threadIdx.x;
    if (t < E) {
        int s = e[t];
        int d = e[E + t];
        atomicOr(&bm[(size_t)s * WPR + (d >> 5)], 1u << (d & 31));
    }
}

// ---------------- bitmap -> CSR + dinv + prescaled x (one wave/row) ----------------
__global__ void __launch_bounds__(256) build_csr(const unsigned* __restrict__ bm,
                                                 int* __restrict__ nbr, int* __restrict__ cnt,
                                                 float* __restrict__ dinv,
                                                 const float* __restrict__ x,
                                                 float* __restrict__ xs) {
    int wave = (blockIdx.x * blockDim.x + threadIdx.x) >> 6;
    int lane = threadIdx.x & 63;
    if (wave >= N_NODES) return;
    int i = wave;
    const unsigned* row = bm + (size_t)i * WPR;
    int* outl = nbr + (size_t)i * CAP;
    int running = 0;
    #pragma unroll
    for (int step = 0; step < 5; ++step) {           // 5*64 == 320 == WPR
        unsigned bits = row[step * 64 + lane];
        int n = __popc(bits);
        int off = n;                                  // inclusive prefix over 64 lanes
        #pragma unroll
        for (int d = 1; d < 64; d <<= 1) {
            int v = __shfl_up(off, d);
            if (lane >= d) off += v;
        }
        int total = __shfl(off, 63);
        int slot = running + off - n;                 // exclusive prefix
        int w = step * 64 + lane;
        while (bits) {
            int b = __ffs(bits) - 1; bits &= bits - 1;
            if (slot < CAP) outl[slot] = (w << 5) + b;
            slot++;
        }
        running += total;
    }
    float di = rsqrtf((float)(running + 1) + DEG_EPS);   // +1 from added identity
    if (lane == 0) { cnt[i] = running < CAP ? running : CAP; dinv[i] = di; }
    if (lane < 6) xs[(size_t)i * 6 + lane] = di * x[(size_t)i * 6 + lane];
}

// ---------------- agg1 (dim 6) + GEMM W0 + BN1 per-block partials ----------------
__global__ void __launch_bounds__(256) agg1_gemm_bn(const int* __restrict__ nbr,
                                                    const int* __restrict__ cnt,
                                                    const float* __restrict__ dinv,
                                                    const float* __restrict__ xs,
                                                    const float* __restrict__ W0,
                                                    const float* __restrict__ b0,
                                                    float* __restrict__ hA,
                                                    float* __restrict__ p1s,
                                                    float* __restrict__ p1q) {
    int tid = threadIdx.x;
    int lane = tid & 63;
    int gw = blockIdx.x * 4 + (tid >> 6);
    float ps = 0.f, pq = 0.f;
    for (int i = gw; i < N_NODES; i += NAGG * 4) {
        int c = cnt[i];
        const int* lst = nbr + (size_t)i * CAP;
        float acc[6] = {0.f, 0.f, 0.f, 0.f, 0.f, 0.f};
        for (int k = lane; k < c; k += 64) {
            int j = lst[k];
            const float* xj = xs + (size_t)j * 6;
            #pragma unroll
            for (int d = 0; d < 6; ++d) acc[d] += xj[d];
        }
        #pragma unroll
        for (int d = 0; d < 6; ++d) {
            #pragma unroll
            for (int off = 32; off; off >>= 1) acc[d] += __shfl_xor(acc[d], off);
        }
        float di = dinv[i];
        if (lane < 32) {
            float s = b0[lane];
            #pragma unroll
            for (int d = 0; d < 6; ++d)
                s += (acc[d] + xs[(size_t)i * 6 + d]) * di * W0[d * 32 + lane];
            hA[(size_t)i * 32 + lane] = s;
            ps += s; pq += s * s;
        }
    }
    __shared__ float ls[256], lq[256];
    ls[tid] = ps; lq[tid] = pq;
    __syncthreads();
    if (tid < 32) {
        float s = 0.f, q = 0.f;
        #pragma unroll
        for (int k = 0; k < 8; ++k) { s += ls[k * 32 + tid]; q += lq[k * 32 + tid]; }
        p1s[blockIdx.x * 32 + tid] = s;
        p1q[blockIdx.x * 32 + tid] = q;
    }
}

// ---------------- BN1: redundant partial-reduce + apply + ReLU + prescale ----------------
__global__ void __launch_bounds__(256) bn1_apply(const float* __restrict__ hA,
                                                 const float* __restrict__ p1s,
                                                 const float* __restrict__ p1q,
                                                 const float* __restrict__ g0,
                                                 const float* __restrict__ be0,
                                                 const float* __restrict__ dinv,
                                                 float* __restrict__ hB,
                                                 float* __restrict__ hBs) {
    __shared__ float ls[256], lq[256];
    __shared__ float sc[32], sh[32];
    int tid = threadIdx.x;
    int f = tid & 31, seg = tid >> 5;                 // 8 segs of 64 blocks
    float s = 0.f, q = 0.f;
    for (int b = seg * 64; b < seg * 64 + 64; ++b) {  // coalesced: addr = b*32+f
        s += p1s[b * 32 + f];
        q += p1q[b * 32 + f];
    }
    ls[tid] = s; lq[tid] = q;
    __syncthreads();
    if (tid < 32) {
        float S = 0.f, Q = 0.f;
        #pragma unroll
        for (int k = 0; k < 8; ++k) { S += ls[k * 32 + tid]; Q += lq[k * 32 + tid]; }
        float mu = S / (float)N_NODES;
        float var = Q / (float)N_NODES - mu * mu;     // biased
        float rstd = rsqrtf(var + BN_EPS);
        float scale = g0[tid] * rstd;
        sc[tid] = scale; sh[tid] = be0[tid] - mu * scale;
    }
    __syncthreads();
    for (int idx = blockIdx.x * 256 + tid; idx < N_NODES * 32; idx += NAPL * 256) {
        int ff = idx & 31;
        float v = hA[idx] * sc[ff] + sh[ff];
        v = v > 0.f ? v : 0.f;
        hB[idx] = v;                                  // residual input
        hBs[idx] = v * dinv[idx >> 5];                // prescaled for agg2
    }
}

// ---------------- agg2 (dim 32) + GEMM W1 + BN2 partials ----------------
// ILP body is WAVE-UNIFORM (guard depends only on wave-uniform cF), so the
// __shfl sources are always exec-active. Tail uses direct loads only.
__global__ void __launch_bounds__(256) agg2_gemm_bn(const int* __restrict__ nbr,
                                                    const int* __restrict__ cnt,
                                                    const float* __restrict__ dinv,
                                                    const float* __restrict__ hBs,
                                                    const float* __restrict__ W1,
                                                    const float* __restrict__ b1,
                                                    float* __restrict__ hA,
                                                    float* __restrict__ p2s,
                                                    float* __restrict__ p2q) {
    int tid = threadIdx.x;
    int lane = tid & 63;
    int gw = blockIdx.x * 4 + (tid >> 6);
    int f = lane & 31, half = lane >> 5;
    float ps = 0.f, pq = 0.f;
    for (int i = gw; i < N_NODES; i += NAGG * 4) {
        int c = cnt[i];
        const int* lst = nbr + (size_t)i * CAP;
        int idxA = lst[lane];                          // coalesced 256B load
        int cF = c < 64 ? c : 64;                      // wave-uniform
        float acc = 0.f;
        int kb = 0;
        for (; kb + 8 <= cF; kb += 8) {                // uniform trip count
            int j0 = __shfl(idxA, kb + half);
            int j1 = __shfl(idxA, kb + half + 2);
            int j2 = __shfl(idxA, kb + half + 4);
            int j3 = __shfl(idxA, kb + half + 6);
            float v0 = hBs[(size_t)j0 * 32 + f];
            float v1 = hBs[(size_t)j1 * 32 + f];
            float v2 = hBs[(size_t)j2 * 32 + f];
            float v3 = hBs[(size_t)j3 * 32 + f];
            acc += v0 + v1 + v2 + v3;
        }
        for (int k = kb + half; k < c; k += 2)         // tail: no cross-lane ops
            acc += hBs[(size_t)lst[k] * 32 + f];
        acc += __shfl_xor(acc, 32);                    // combine halves
        float t = (acc + hBs[(size_t)i * 32 + f]) * dinv[i];
        float part = 0.f;
        int fbase = half * 16;
        #pragma unroll
        for (int kk = 0; kk < 16; ++kk)
            part += __shfl(t, fbase + kk) * W1[(fbase + kk) * 32 + f];
        part += __shfl_xor(part, 32);
        if (lane < 32) {
            float sv = b1[f] + part;
            hA[(size_t)i * 32 + f] = sv;
            ps += sv; pq += sv * sv;
        }
    }
    __shared__ float ls[256], lq[256];
    ls[tid] = ps; lq[tid] = pq;
    __syncthreads();
    if (tid < 32) {
        float s = 0.f, q = 0.f;
        #pragma unroll
        for (int k = 0; k < 8; ++k) { s += ls[k * 32 + tid]; q += lq[k * 32 + tid]; }
        p2s[blockIdx.x * 32 + tid] = s;
        p2q[blockIdx.x * 32 + tid] = q;
    }
}

// ---------------- final: BN2 reduce+apply + ReLU + residual + heads ----------------
__global__ void __launch_bounds__(256) final_fused(const float* __restrict__ hA,
                                                   const float* __restrict__ p2s,
                                                   const float* __restrict__ p2q,
                                                   const float* __restrict__ g1,
                                                   const float* __restrict__ be1,
                                                   const float* __restrict__ hB,
                                                   const float* __restrict__ Wo,
                                                   const float* __restrict__ bo,
                                                   const float* __restrict__ Wa,
                                                   const float* __restrict__ ba,
                                                   float* __restrict__ out) {
    __shared__ float ls[256], lq[256];
    __shared__ float sc[32], sh[32];
    int tid = threadIdx.x;
    int f = tid & 31, seg = tid >> 5;
    float s = 0.f, q = 0.f;
    for (int b = seg * 64; b < seg * 64 + 64; ++b) {
        s += p2s[b * 32 + f];
        q += p2q[b * 32 + f];
    }
    ls[tid] = s; lq[tid] = q;
    __syncthreads();
    if (tid < 32) {
        float S = 0.f, Q = 0.f;
        #pragma unroll
        for (int k = 0; k < 8; ++k) { S += ls[k * 32 + tid]; Q += lq[k * 32 + tid]; }
        float mu = S / (float)N_NODES;
        float var = Q / (float)N_NODES - mu * mu;
        float rstd = rsqrtf(var + BN_EPS);
        float scale = g1[tid] * rstd;
        sc[tid] = scale; sh[tid] = be1[tid] - mu * scale;
    }
    __syncthreads();
    const int l = tid & 31;
    for (int r = (blockIdx.x * 256 + tid) >> 5; r < N_NODES; r += NAPL * 8) {
        int idx = r * 32 + l;
        float v = hA[idx] * sc[l] + sh[l];
        v = v > 0.f ? v : 0.f;
        v += hB[idx];                                  // residual -> final h
        float q0 = v * Wo[l * 2 + 0];
        float q1 = v * Wo[l * 2 + 1];
        float qa = v * Wa[l];
        #pragma unroll
        for (int off = 16; off; off >>= 1) {
            q0 += __shfl_xor(q0, off);
            q1 += __shfl_xor(q1, off);
            qa += __shfl_xor(qa, off);
        }
        if (l == 0) {
            out[(size_t)r * 2 + 0] = q0 + bo[0];
            out[(size_t)r * 2 + 1] = q1 + bo[1];
            out[2 * N_NODES + r] = 1.f / (1.f + expf(-(qa + ba[0])));
        }
    }
}

extern "C" void kernel_launch(void* const* d_in, const int* in_sizes, int n_in,
                              void* d_out, int out_size, void* d_ws, size_t ws_size,
                              hipStream_t stream) {
    const float* x   = (const float*)d_in[0];
    const int*  eidx = (const int*)d_in[1];
    const int E = in_sizes[1] / 2;
    const float* W0 = (const float*)d_in[2];
    const float* b0 = (const float*)d_in[3];
    const float* g0 = (const float*)d_in[4];
    const float* be0= (const float*)d_in[5];
    const float* W1 = (const float*)d_in[6];
    const float* b1 = (const float*)d_in[7];
    const float* g1 = (const float*)d_in[8];
    const float* be1= (const float*)d_in[9];
    const float* Wo = (const float*)d_in[10];
    const float* bo = (const float*)d_in[11];
    const float* Wa = (const float*)d_in[12];
    const float* ba = (const float*)d_in[13];
    float* out = (float*)d_out;

    char* ws = (char*)d_ws;
    size_t off = 0;
    auto take = [&](size_t bytes) { char* q = ws + off; off += (bytes + 255) & ~(size_t)255; return q; };
    unsigned* bm = (unsigned*)take((size_t)N_NODES * WPR * 4);   // 12.8 MB
    int* nbr  = (int*)take((size_t)N_NODES * CAP * 4);           // 3.84 MB
    int* cntb = (int*)take((size_t)N_NODES * 4);
    float* dinv = (float*)take((size_t)N_NODES * 4);
    float* xs = (float*)take((size_t)N_NODES * 6 * 4);
    float* hA = (float*)take((size_t)N_NODES * 32 * 4);
    float* hB = (float*)take((size_t)N_NODES * 32 * 4);
    float* hBs= (float*)take((size_t)N_NODES * 32 * 4);
    float* p1s= (float*)take(NAGG * 32 * 4);
    float* p1q= (float*)take(NAGG * 32 * 4);
    float* p2s= (float*)take(NAGG * 32 * 4);
    float* p2q= (float*)take(NAGG * 32 * 4);

    hipMemsetAsync(bm, 0, (size_t)N_NODES * WPR * 4, stream);
    scatter_edges<<<(E + 255) / 256, 256, 0, stream>>>(eidx, E, bm);
    build_csr<<<2500, 256, 0, stream>>>(bm, nbr, cntb, dinv, x, xs);
    agg1_gemm_bn<<<NAGG, 256, 0, stream>>>(nbr, cntb, dinv, xs, W0, b0, hA, p1s, p1q);
    bn1_apply<<<NAPL, 256, 0, stream>>>(hA, p1s, p1q, g0, be0, dinv, hB, hBs);
    agg2_gemm_bn<<<NAGG, 256, 0, stream>>>(nbr, cntb, dinv, hBs, W1, b1, hA, p2s, p2q);
    final_fused<<<NAPL, 256, 0, stream>>>(hA, p2s, p2q, g1, be1, hB, Wo, bo, Wa, ba, out);
}

// Round 7
// 109.616 us; speedup vs baseline: 3.0099x; 1.0034x over previous
//
#include <hip/hip_runtime.h>
#include <math.h>

#define N_NODES 10000
#define WPR 320            // padded: 1280B-aligned bitmap rows, 5*64 covers exactly
#define CAP 96             // neighbor capacity (deg ~ mean 32, sd 5.7; max ~56 expected)
#define BN_EPS 1e-5f
#define DEG_EPS 1e-8f
#define NAGG 512           // blocks for agg kernels (2048 waves, 8 waves/CU)
#define NAPL 320           // blocks for apply/final kernels

// ---------------- bitmap clear (own kernel: rocclr fill runs at 300 GB/s for 12.8MB) ----------------
__global__ void __launch_bounds__(256) clear_bitmap(uint4* __restrict__ bm) {
    int t = blockIdx.x * blockDim.x + threadIdx.x;   // exactly 800000 uint4s
    if (t < N_NODES * WPR / 4) bm[t] = make_uint4(0u, 0u, 0u, 0u);
}

// ---------------- scatter edges (SET semantics via atomicOr) ----------------
__global__ void __launch_bounds__(256) scatter_edges(const int* __restrict__ e, int E,
                                                     unsigned* __restrict__ bm) {
    int t = blockIdx.x * blockDim.x + threadIdx.x;
    if (t < E) {
        int s = e[t];
        int d = e[E + t];
        atomicOr(&bm[(size_t)s * WPR + (d >> 5)], 1u << (d & 31));
    }
}

// ---------------- bitmap -> CSR + dinv + prescaled x (one wave/row) ----------------
__global__ void __launch_bounds__(256) build_csr(const unsigned* __restrict__ bm,
                                                 int* __restrict__ nbr, int* __restrict__ cnt,
                                                 float* __restrict__ dinv,
                                                 const float* __restrict__ x,
                                                 float* __restrict__ xs) {
    int wave = (blockIdx.x * blockDim.x + threadIdx.x) >> 6;
    int lane = threadIdx.x & 63;
    if (wave >= N_NODES) return;
    int i = wave;
    const unsigned* row = bm + (size_t)i * WPR;
    int* outl = nbr + (size_t)i * CAP;
    int running = 0;
    #pragma unroll
    for (int step = 0; step < 5; ++step) {           // 5*64 == 320 == WPR
        unsigned bits = row[step * 64 + lane];
        int n = __popc(bits);
        int off = n;                                  // inclusive prefix over 64 lanes
        #pragma unroll
        for (int d = 1; d < 64; d <<= 1) {
            int v = __shfl_up(off, d);
            if (lane >= d) off += v;
        }
        int total = __shfl(off, 63);
        int slot = running + off - n;                 // exclusive prefix
        int w = step * 64 + lane;
        while (bits) {
            int b = __ffs(bits) - 1; bits &= bits - 1;
            if (slot < CAP) outl[slot] = (w << 5) + b;
            slot++;
        }
        running += total;
    }
    float di = rsqrtf((float)(running + 1) + DEG_EPS);   // +1 from added identity
    if (lane == 0) { cnt[i] = running < CAP ? running : CAP; dinv[i] = di; }
    if (lane < 6) xs[(size_t)i * 6 + lane] = di * x[(size_t)i * 6 + lane];
}

// ---------------- agg1 (dim 6) + GEMM W0 + BN1 per-block partials ----------------
__global__ void __launch_bounds__(256) agg1_gemm_bn(const int* __restrict__ nbr,
                                                    const int* __restrict__ cnt,
                                                    const float* __restrict__ dinv,
                                                    const float* __restrict__ xs,
                                                    const float* __restrict__ W0,
                                                    const float* __restrict__ b0,
                                                    float* __restrict__ hA,
                                                    float* __restrict__ p1s,
                                                    float* __restrict__ p1q) {
    int tid = threadIdx.x;
    int lane = tid & 63;
    int gw = blockIdx.x * 4 + (tid >> 6);
    float ps = 0.f, pq = 0.f;
    for (int i = gw; i < N_NODES; i += NAGG * 4) {
        int c = cnt[i];
        const int* lst = nbr + (size_t)i * CAP;
        float acc[6] = {0.f, 0.f, 0.f, 0.f, 0.f, 0.f};
        for (int k = lane; k < c; k += 64) {
            int j = lst[k];
            const float* xj = xs + (size_t)j * 6;
            #pragma unroll
            for (int d = 0; d < 6; ++d) acc[d] += xj[d];
        }
        #pragma unroll
        for (int d = 0; d < 6; ++d) {
            #pragma unroll
            for (int off = 32; off; off >>= 1) acc[d] += __shfl_xor(acc[d], off);
        }
        float di = dinv[i];
        if (lane < 32) {
            float s = b0[lane];
            #pragma unroll
            for (int d = 0; d < 6; ++d)
                s += (acc[d] + xs[(size_t)i * 6 + d]) * di * W0[d * 32 + lane];
            hA[(size_t)i * 32 + lane] = s;
            ps += s; pq += s * s;
        }
    }
    __shared__ float ls[256], lq[256];
    ls[tid] = ps; lq[tid] = pq;
    __syncthreads();
    if (tid < 32) {
        float s = 0.f, q = 0.f;
        #pragma unroll
        for (int k = 0; k < 8; ++k) { s += ls[k * 32 + tid]; q += lq[k * 32 + tid]; }
        p1s[blockIdx.x * 32 + tid] = s;
        p1q[blockIdx.x * 32 + tid] = q;
    }
}

// ---------------- BN1: redundant partial-reduce + apply + ReLU + prescale ----------------
__global__ void __launch_bounds__(256) bn1_apply(const float* __restrict__ hA,
                                                 const float* __restrict__ p1s,
                                                 const float* __restrict__ p1q,
                                                 const float* __restrict__ g0,
                                                 const float* __restrict__ be0,
                                                 const float* __restrict__ dinv,
                                                 float* __restrict__ hB,
                                                 float* __restrict__ hBs) {
    __shared__ float ls[256], lq[256];
    __shared__ float sc[32], sh[32];
    int tid = threadIdx.x;
    int f = tid & 31, seg = tid >> 5;                 // 8 segs of 64 blocks
    float s = 0.f, q = 0.f;
    for (int b = seg * 64; b < seg * 64 + 64; ++b) {  // coalesced: addr = b*32+f
        s += p1s[b * 32 + f];
        q += p1q[b * 32 + f];
    }
    ls[tid] = s; lq[tid] = q;
    __syncthreads();
    if (tid < 32) {
        float S = 0.f, Q = 0.f;
        #pragma unroll
        for (int k = 0; k < 8; ++k) { S += ls[k * 32 + tid]; Q += lq[k * 32 + tid]; }
        float mu = S / (float)N_NODES;
        float var = Q / (float)N_NODES - mu * mu;     // biased
        float rstd = rsqrtf(var + BN_EPS);
        float scale = g0[tid] * rstd;
        sc[tid] = scale; sh[tid] = be0[tid] - mu * scale;
    }
    __syncthreads();
    for (int idx = blockIdx.x * 256 + tid; idx < N_NODES * 32; idx += NAPL * 256) {
        int ff = idx & 31;
        float v = hA[idx] * sc[ff] + sh[ff];
        v = v > 0.f ? v : 0.f;
        hB[idx] = v;                                  // residual input
        hBs[idx] = v * dinv[idx >> 5];                // prescaled for agg2
    }
}

// ---------------- agg2 (dim 32) + GEMM W1 + BN2 partials ----------------
// ILP body is WAVE-UNIFORM (guard depends only on wave-uniform cF), so the
// __shfl sources are always exec-active. Tail uses direct loads only.
__global__ void __launch_bounds__(256) agg2_gemm_bn(const int* __restrict__ nbr,
                                                    const int* __restrict__ cnt,
                                                    const float* __restrict__ dinv,
                                                    const float* __restrict__ hBs,
                                                    const float* __restrict__ W1,
                                                    const float* __restrict__ b1,
                                                    float* __restrict__ hA,
                                                    float* __restrict__ p2s,
                                                    float* __restrict__ p2q) {
    int tid = threadIdx.x;
    int lane = tid & 63;
    int gw = blockIdx.x * 4 + (tid >> 6);
    int f = lane & 31, half = lane >> 5;
    float ps = 0.f, pq = 0.f;
    for (int i = gw; i < N_NODES; i += NAGG * 4) {
        int c = cnt[i];
        const int* lst = nbr + (size_t)i * CAP;
        int idxA = lst[lane];                          // coalesced 256B load
        int cF = c < 64 ? c : 64;                      // wave-uniform
        float acc = 0.f;
        int kb = 0;
        for (; kb + 8 <= cF; kb += 8) {                // uniform trip count
            int j0 = __shfl(idxA, kb + half);
            int j1 = __shfl(idxA, kb + half + 2);
            int j2 = __shfl(idxA, kb + half + 4);
            int j3 = __shfl(idxA, kb + half + 6);
            float v0 = hBs[(size_t)j0 * 32 + f];
            float v1 = hBs[(size_t)j1 * 32 + f];
            float v2 = hBs[(size_t)j2 * 32 + f];
            float v3 = hBs[(size_t)j3 * 32 + f];
            acc += v0 + v1 + v2 + v3;
        }
        for (int k = kb + half; k < c; k += 2)         // tail: no cross-lane ops
            acc += hBs[(size_t)lst[k] * 32 + f];
        acc += __shfl_xor(acc, 32);                    // combine halves
        float t = (acc + hBs[(size_t)i * 32 + f]) * dinv[i];
        float part = 0.f;
        int fbase = half * 16;
        #pragma unroll
        for (int kk = 0; kk < 16; ++kk)
            part += __shfl(t, fbase + kk) * W1[(fbase + kk) * 32 + f];
        part += __shfl_xor(part, 32);
        if (lane < 32) {
            float sv = b1[f] + part;
            hA[(size_t)i * 32 + f] = sv;
            ps += sv; pq += sv * sv;
        }
    }
    __shared__ float ls[256], lq[256];
    ls[tid] = ps; lq[tid] = pq;
    __syncthreads();
    if (tid < 32) {
        float s = 0.f, q = 0.f;
        #pragma unroll
        for (int k = 0; k < 8; ++k) { s += ls[k * 32 + tid]; q += lq[k * 32 + tid]; }
        p2s[blockIdx.x * 32 + tid] = s;
        p2q[blockIdx.x * 32 + tid] = q;
    }
}

// ---------------- final: BN2 reduce+apply + ReLU + residual + heads ----------------
__global__ void __launch_bounds__(256) final_fused(const float* __restrict__ hA,
                                                   const float* __restrict__ p2s,
                                                   const float* __restrict__ p2q,
                                                   const float* __restrict__ g1,
                                                   const float* __restrict__ be1,
                                                   const float* __restrict__ hB,
                                                   const float* __restrict__ Wo,
                                                   const float* __restrict__ bo,
                                                   const float* __restrict__ Wa,
                                                   const float* __restrict__ ba,
                                                   float* __restrict__ out) {
    __shared__ float ls[256], lq[256];
    __shared__ float sc[32], sh[32];
    int tid = threadIdx.x;
    int f = tid & 31, seg = tid >> 5;
    float s = 0.f, q = 0.f;
    for (int b = seg * 64; b < seg * 64 + 64; ++b) {
        s += p2s[b * 32 + f];
        q += p2q[b * 32 + f];
    }
    ls[tid] = s; lq[tid] = q;
    __syncthreads();
    if (tid < 32) {
        float S = 0.f, Q = 0.f;
        #pragma unroll
        for (int k = 0; k < 8; ++k) { S += ls[k * 32 + tid]; Q += lq[k * 32 + tid]; }
        float mu = S / (float)N_NODES;
        float var = Q / (float)N_NODES - mu * mu;
        float rstd = rsqrtf(var + BN_EPS);
        float scale = g1[tid] * rstd;
        sc[tid] = scale; sh[tid] = be1[tid] - mu * scale;
    }
    __syncthreads();
    const int l = tid & 31;
    for (int r = (blockIdx.x * 256 + tid) >> 5; r < N_NODES; r += NAPL * 8) {
        int idx = r * 32 + l;
        float v = hA[idx] * sc[l] + sh[l];
        v = v > 0.f ? v : 0.f;
        v += hB[idx];                                  // residual -> final h
        float q0 = v * Wo[l * 2 + 0];
        float q1 = v * Wo[l * 2 + 1];
        float qa = v * Wa[l];
        #pragma unroll
        for (int off = 16; off; off >>= 1) {
            q0 += __shfl_xor(q0, off);
            q1 += __shfl_xor(q1, off);
            qa += __shfl_xor(qa, off);
        }
        if (l == 0) {
            out[(size_t)r * 2 + 0] = q0 + bo[0];
            out[(size_t)r * 2 + 1] = q1 + bo[1];
            out[2 * N_NODES + r] = 1.f / (1.f + expf(-(qa + ba[0])));
        }
    }
}

extern "C" void kernel_launch(void* const* d_in, const int* in_sizes, int n_in,
                              void* d_out, int out_size, void* d_ws, size_t ws_size,
                              hipStream_t stream) {
    const float* x   = (const float*)d_in[0];
    const int*  eidx = (const int*)d_in[1];
    const int E = in_sizes[1] / 2;
    const float* W0 = (const float*)d_in[2];
    const float* b0 = (const float*)d_in[3];
    const float* g0 = (const float*)d_in[4];
    const float* be0= (const float*)d_in[5];
    const float* W1 = (const float*)d_in[6];
    const float* b1 = (const float*)d_in[7];
    const float* g1 = (const float*)d_in[8];
    const float* be1= (const float*)d_in[9];
    const float* Wo = (const float*)d_in[10];
    const float* bo = (const float*)d_in[11];
    const float* Wa = (const float*)d_in[12];
    const float* ba = (const float*)d_in[13];
    float* out = (float*)d_out;

    char* ws = (char*)d_ws;
    size_t off = 0;
    auto take = [&](size_t bytes) { char* q = ws + off; off += (bytes + 255) & ~(size_t)255; return q; };
    unsigned* bm = (unsigned*)take((size_t)N_NODES * WPR * 4);   // 12.8 MB
    int* nbr  = (int*)take((size_t)N_NODES * CAP * 4);           // 3.84 MB
    int* cntb = (int*)take((size_t)N_NODES * 4);
    float* dinv = (float*)take((size_t)N_NODES * 4);
    float* xs = (float*)take((size_t)N_NODES * 6 * 4);
    float* hA = (float*)take((size_t)N_NODES * 32 * 4);
    float* hB = (float*)take((size_t)N_NODES * 32 * 4);
    float* hBs= (float*)take((size_t)N_NODES * 32 * 4);
    float* p1s= (float*)take(NAGG * 32 * 4);
    float* p1q= (float*)take(NAGG * 32 * 4);
    float* p2s= (float*)take(NAGG * 32 * 4);
    float* p2q= (float*)take(NAGG * 32 * 4);

    const int n16 = N_NODES * WPR / 4;                           // 800000
    clear_bitmap<<<(n16 + 255) / 256, 256, 0, stream>>>((uint4*)bm);
    scatter_edges<<<(E + 255) / 256, 256, 0, stream>>>(eidx, E, bm);
    build_csr<<<2500, 256, 0, stream>>>(bm, nbr, cntb, dinv, x, xs);
    agg1_gemm_bn<<<NAGG, 256, 0, stream>>>(nbr, cntb, dinv, xs, W0, b0, hA, p1s, p1q);
    bn1_apply<<<NAPL, 256, 0, stream>>>(hA, p1s, p1q, g0, be0, dinv, hB, hBs);
    agg2_gemm_bn<<<NAGG, 256, 0, stream>>>(nbr, cntb, dinv, hBs, W1, b1, hA, p2s, p2q);
    final_fused<<<NAPL, 256, 0, stream>>>(hA, p2s, p2q, g1, be1, hB, Wo, bo, Wa, ba, out);
}